// Round 5
// baseline (150.973 us; speedup 1.0000x reference)
//
#include <hip/hip_runtime.h>

// Problem constants
constexpr int N_ = 512, D_ = 64, C_ = 32, HID_ = 128, HEADS_ = 8, HD_ = 16;
constexpr int BT_ = 96;
constexpr float LSCALE_ = 0.25f * 1.4426950408889634f;  // SCALE * log2(e), folded into Wq

typedef __attribute__((ext_vector_type(8))) short short8;
typedef __attribute__((ext_vector_type(4))) float f32x4;

union U8 { short8 s8; unsigned u[4]; };

// Single-instruction pack of 2 f32 -> 2 bf16 (RNE). No builtin on gfx950 (T12).
static __device__ __forceinline__ unsigned cvtpk(float lo, float hi) {
    unsigned r;
    asm("v_cvt_pk_bf16_f32 %0, %1, %2" : "=v"(r) : "v"(lo), "v"(hi));
    return r;
}

static __device__ __forceinline__ float fexp2(float x) {
#if __has_builtin(__builtin_amdgcn_exp2f)
    return __builtin_amdgcn_exp2f(x);
#else
    return exp2f(x);
#endif
}

// V key-permutation within each 32-block: storage slot s holds key kappa(s):
//   s = g*8+i, i<4 -> key g*4+i ; i>=4 -> key 16 + g*4 + (i-4)
static __device__ __forceinline__ int vperm(int b) {   // key%32 -> storage slot
    return (b < 16) ? ((b >> 2) * 8 + (b & 3))
                    : (((b - 16) >> 2) * 8 + 4 + ((b - 16) & 3));
}

// ===== Fused QKV-projection + attention + cls pooling, one block per (bt,h) =====
// grid 768, XCD-swizzled (all 8 heads of a bt share an XCD's L2 for x/cls).
// LDS: ws 6.75KB + k_lds 20KB + vt 16.25KB + den 2KB = ~46KB -> 3 blocks/CU.
__global__ __launch_bounds__(256)
void fused_attn(const float* __restrict__ x,
                const float* __restrict__ cls_map,
                const float* __restrict__ Wq, const float* __restrict__ Wk,
                const float* __restrict__ Wv,
                float* __restrict__ out) {
    __shared__ unsigned short ws[48 * 72];      // W head-slices bf16 (Q:0-15 scaled, K:16-31, V:32-47)
    __shared__ unsigned short k_lds[512 * 20];  // K rows, stride 20 (conflict-free); later sxT
    __shared__ unsigned short vt[16 * 520];     // V^T permuted, stride 520; later part[]
    __shared__ float den[512];                  // 1/denominator per query row

    const int tid = threadIdx.x;
    const int xcd = blockIdx.x & 7, slot = blockIdx.x >> 3;
    const int bt = xcd * 12 + (slot % 12), h = slot / 12;

    const float* __restrict__ xbt  = x + (size_t)bt * N_ * D_;
    const float* __restrict__ clsb = cls_map + (size_t)bt * C_ * N_;

    // ---- stage W head-slices (48 rows x 64 fp32 = 768 float4, 3/thread) ----
    for (int k = 0; k < 3; ++k) {
        const int f = tid + k * 256;            // 0..767
        const int m = f >> 4, c4 = f & 15;      // m 0..47
        const float* src = (m < 16) ? (Wq + (h * 16 + m) * 64)
                         : (m < 32) ? (Wk + (h * 16 + m - 16) * 64)
                                    : (Wv + (h * 16 + m - 32) * 64);
        const float4 w4 = *(const float4*)(src + c4 * 4);
        const float sc = (m < 16) ? LSCALE_ : 1.0f;
        uint2 t;
        t.x = cvtpk(w4.x * sc, w4.y * sc);
        t.y = cvtpk(w4.z * sc, w4.w * sc);
        *(uint2*)(ws + m * 72 + c4 * 4) = t;
    }
    __syncthreads();

    const int lane = tid & 63, w = tid >> 6;
    const int g = lane >> 4, l15 = lane & 15;
    const int qbase = w * 128;
    const f32x4 zf = {0.f, 0.f, 0.f, 0.f};

    // ---- projection: wave w produces rows qbase..qbase+127 (8 tiles of 16) ----
    // B-frag = x^T from global (fp32->bf16 in reg); A-frag = W from LDS.
    short8 qf[8];
    for (int nt = 0; nt < 8; ++nt) {
        const int n = qbase + nt * 16 + l15;
        const float* xr = xbt + n * 64;
        const float4 xa = *(const float4*)(xr + g * 8);
        const float4 xb = *(const float4*)(xr + g * 8 + 4);
        const float4 xc = *(const float4*)(xr + 32 + g * 8);
        const float4 xd = *(const float4*)(xr + 32 + g * 8 + 4);
        U8 b0, b1;
        b0.u[0] = cvtpk(xa.x, xa.y); b0.u[1] = cvtpk(xa.z, xa.w);
        b0.u[2] = cvtpk(xb.x, xb.y); b0.u[3] = cvtpk(xb.z, xb.w);
        b1.u[0] = cvtpk(xc.x, xc.y); b1.u[1] = cvtpk(xc.z, xc.w);
        b1.u[2] = cvtpk(xd.x, xd.y); b1.u[3] = cvtpk(xd.z, xd.w);

        // Q (channels 0-15): C[ch=g*4+r][row=l15] -> B-frag[k=ch g*8+i][n=row] via 4 shfl
        {
            const unsigned short* wr = ws + l15 * 72;
            const short8 a0 = *(const short8*)(wr + g * 8);
            const short8 a1 = *(const short8*)(wr + 32 + g * 8);
            f32x4 acc = zf;
            acc = __builtin_amdgcn_mfma_f32_16x16x32_bf16(a0, b0.s8, acc, 0, 0, 0);
            acc = __builtin_amdgcn_mfma_f32_16x16x32_bf16(a1, b1.s8, acc, 0, 0, 0);
            const unsigned u = cvtpk(acc[0], acc[1]), v = cvtpk(acc[2], acc[3]);
            const int s0 = (g * 32 + l15) & 63;        // lane holding ch 8g..8g+3, row l15
            const int s1 = (g * 32 + 16 + l15) & 63;   // lane holding ch 8g+4..8g+7
            U8 q;
            q.u[0] = (unsigned)__shfl((int)u, s0, 64);
            q.u[1] = (unsigned)__shfl((int)v, s0, 64);
            q.u[2] = (unsigned)__shfl((int)u, s1, 64);
            q.u[3] = (unsigned)__shfl((int)v, s1, 64);
            if (g >= 2) { q.u[0] = q.u[1] = q.u[2] = q.u[3] = 0u; }  // k-dim zero pad
            qf[nt] = q.s8;
        }
        // K (channels 16-31): write K[row][ch] to k_lds, stride 20
        {
            const unsigned short* wr = ws + (16 + l15) * 72;
            const short8 a0 = *(const short8*)(wr + g * 8);
            const short8 a1 = *(const short8*)(wr + 32 + g * 8);
            f32x4 acc = zf;
            acc = __builtin_amdgcn_mfma_f32_16x16x32_bf16(a0, b0.s8, acc, 0, 0, 0);
            acc = __builtin_amdgcn_mfma_f32_16x16x32_bf16(a1, b1.s8, acc, 0, 0, 0);
            uint2 t;
            t.x = cvtpk(acc[0], acc[1]);
            t.y = cvtpk(acc[2], acc[3]);
            *(uint2*)(k_lds + n * 20 + g * 4) = t;
        }
        // V (channels 32-47): scatter V^T[d][slot] with key-permutation
        {
            const unsigned short* wr = ws + (32 + l15) * 72;
            const short8 a0 = *(const short8*)(wr + g * 8);
            const short8 a1 = *(const short8*)(wr + 32 + g * 8);
            f32x4 acc = zf;
            acc = __builtin_amdgcn_mfma_f32_16x16x32_bf16(a0, b0.s8, acc, 0, 0, 0);
            acc = __builtin_amdgcn_mfma_f32_16x16x32_bf16(a1, b1.s8, acc, 0, 0, 0);
            const int blk = n >> 5;                        // 32-key block
            const int sl = vperm(((nt & 1) << 4) + l15);   // n & 31 = (nt&1)*16 + l15
            const unsigned u0 = cvtpk(acc[0], acc[1]);
            const unsigned u1 = cvtpk(acc[2], acc[3]);
            unsigned short* vr = vt + blk * 32 + sl;
            vr[(g * 4 + 0) * 520] = (unsigned short)(u0 & 0xffffu);
            vr[(g * 4 + 1) * 520] = (unsigned short)(u0 >> 16);
            vr[(g * 4 + 2) * 520] = (unsigned short)(u1 & 0xffffu);
            vr[(g * 4 + 3) * 520] = (unsigned short)(u1 >> 16);
        }
    }
    __syncthreads();   // K/V fully staged

    // ---- attention: S^T = mfma(K, Q); P = exp2(S^T); O^T += mfma(P, V^T) ----
    f32x4 oacc[8];
    float dd[8];
#pragma unroll
    for (int mb = 0; mb < 8; ++mb) { oacc[mb] = zf; dd[mb] = 0.f; }

    for (int j = 0; j < 16; ++j) {               // 32 keys per iter
        U8 ka, kb;
        ka.u[0] = ka.u[1] = ka.u[2] = ka.u[3] = 0u;
        kb.u[0] = kb.u[1] = kb.u[2] = kb.u[3] = 0u;
        if (g < 2) {                             // A[m=key][k=dim], dims 16..31 zero
            const unsigned short* r0 = k_lds + (j * 32 + l15) * 20 + g * 8;
            const unsigned short* r1 = k_lds + (j * 32 + 16 + l15) * 20 + g * 8;
            uint2 lo = *(const uint2*)r0, hi = *(const uint2*)(r0 + 4);
            ka.u[0] = lo.x; ka.u[1] = lo.y; ka.u[2] = hi.x; ka.u[3] = hi.y;
            lo = *(const uint2*)r1; hi = *(const uint2*)(r1 + 4);
            kb.u[0] = lo.x; kb.u[1] = lo.y; kb.u[2] = hi.x; kb.u[3] = hi.y;
        }
        // B-frag for PV: V[key-slot][d] from permuted Vt
        const short8 vf = *(const short8*)(vt + l15 * 520 + j * 32 + g * 8);

#pragma unroll
        for (int mb = 0; mb < 8; ++mb) {
            f32x4 s0 = __builtin_amdgcn_mfma_f32_16x16x32_bf16(ka.s8, qf[mb], zf, 0, 0, 0);
            f32x4 s1 = __builtin_amdgcn_mfma_f32_16x16x32_bf16(kb.s8, qf[mb], zf, 0, 0, 0);
            // lane holds S^T: keys j*32 + {g*4+r} (s0), j*32+16+{g*4+r} (s1), q = l15
            const float e0 = fexp2(s0[0]), e1 = fexp2(s0[1]), e2 = fexp2(s0[2]), e3 = fexp2(s0[3]);
            const float e4 = fexp2(s1[0]), e5 = fexp2(s1[1]), e6 = fexp2(s1[2]), e7 = fexp2(s1[3]);
            dd[mb] += ((e0 + e1) + (e2 + e3)) + ((e4 + e5) + (e6 + e7));
            U8 p;
            p.u[0] = cvtpk(e0, e1);
            p.u[1] = cvtpk(e2, e3);
            p.u[2] = cvtpk(e4, e5);
            p.u[3] = cvtpk(e6, e7);
            oacc[mb] = __builtin_amdgcn_mfma_f32_16x16x32_bf16(p.s8, vf, oacc[mb], 0, 0, 0);
        }
    }

    // denominator: reduce across the 4 lane-groups, write reciprocal
#pragma unroll
    for (int mb = 0; mb < 8; ++mb) {
        float d = dd[mb];
        d += __shfl_xor(d, 16, 64);
        d += __shfl_xor(d, 32, 64);
        if (g == 0) den[qbase + mb * 16 + l15] = 1.0f / d;
    }
    __syncthreads();   // all waves done reading k_lds/vt

    // write unnormalized O^T (bf16) into k_lds region as sxT[16][520]
    unsigned short* sxT = k_lds;
#pragma unroll
    for (int mb = 0; mb < 8; ++mb) {
        uint2 t;
        t.x = cvtpk(oacc[mb][0], oacc[mb][1]);
        t.y = cvtpk(oacc[mb][2], oacc[mb][3]);
        const int q0 = qbase + mb * 16 + g * 4;   // C layout: rows = q, col = d = l15
        *(uint2*)(sxT + l15 * 520 + q0) = t;
    }
    __syncthreads();

    // pooling: out[c][d] = sum_n (cls[c][n]*rden[n]) * O[n][d]; wave w: n-blocks w*4..w*4+3
    f32x4 pacc0 = zf, pacc1 = zf;
    for (int kk = 0; kk < 4; ++kk) {
        const int n0 = (w * 4 + kk) * 32;
        const short8 b8 = *(const short8*)(sxT + l15 * 520 + n0 + g * 8);
        const float4 rd0 = *(const float4*)(den + n0 + g * 8);
        const float4 rd1 = *(const float4*)(den + n0 + g * 8 + 4);
        const float* c0 = clsb + l15 * N_ + n0 + g * 8;
        const float* c1 = clsb + (16 + l15) * N_ + n0 + g * 8;
        float4 ca = *(const float4*)c0, cb = *(const float4*)(c0 + 4);
        U8 a0;
        a0.u[0] = cvtpk(ca.x * rd0.x, ca.y * rd0.y);
        a0.u[1] = cvtpk(ca.z * rd0.z, ca.w * rd0.w);
        a0.u[2] = cvtpk(cb.x * rd1.x, cb.y * rd1.y);
        a0.u[3] = cvtpk(cb.z * rd1.z, cb.w * rd1.w);
        pacc0 = __builtin_amdgcn_mfma_f32_16x16x32_bf16(a0.s8, b8, pacc0, 0, 0, 0);
        ca = *(const float4*)c1; cb = *(const float4*)(c1 + 4);
        U8 a1;
        a1.u[0] = cvtpk(ca.x * rd0.x, ca.y * rd0.y);
        a1.u[1] = cvtpk(ca.z * rd0.z, ca.w * rd0.w);
        a1.u[2] = cvtpk(cb.x * rd1.x, cb.y * rd1.y);
        a1.u[3] = cvtpk(cb.z * rd1.z, cb.w * rd1.w);
        pacc1 = __builtin_amdgcn_mfma_f32_16x16x32_bf16(a1.s8, b8, pacc1, 0, 0, 0);
    }
    // partial reduction across waves via LDS (overlay vt region)
    float* part = (float*)vt;                    // [8][256] = [w*2+mt][row*16+col]
#pragma unroll
    for (int r = 0; r < 4; ++r) {
        part[(w * 2 + 0) * 256 + (g * 4 + r) * 16 + l15] = pacc0[r];
        part[(w * 2 + 1) * 256 + (g * 4 + r) * 16 + l15] = pacc1[r];
    }
    __syncthreads();

    float* ob = out + (size_t)bt * C_ * HID_;
    for (int o = tid; o < 512; o += 256) {
        const int c = o >> 4, dc = o & 15;
        const int mt = c >> 4, rr = c & 15;
        const int idx = mt * 256 + rr * 16 + dc;
        const float s = part[idx] + part[512 + idx] + part[1024 + idx] + part[1536 + idx];
        ob[c * HID_ + h * HD_ + dc] = s;
    }
}

extern "C" void kernel_launch(void* const* d_in, const int* in_sizes, int n_in,
                              void* d_out, int out_size, void* d_ws, size_t ws_size,
                              hipStream_t stream) {
    const float* x       = (const float*)d_in[0];
    const float* cls_map = (const float*)d_in[1];
    const float* Wq      = (const float*)d_in[2];
    const float* Wk      = (const float*)d_in[3];
    const float* Wv      = (const float*)d_in[4];
    float* out           = (float*)d_out;

    fused_attn<<<BT_ * HEADS_, 256, 0, stream>>>(x, cls_map, Wq, Wk, Wv, out);
}